// Round 1
// baseline (114.919 us; speedup 1.0000x reference)
//
#include <hip/hip_runtime.h>
#include <math.h>

#define SLICES 16
#define ROWS_PER_SLICE 32
#define NBOXES 160
#define THREADS 256

static __device__ __forceinline__ unsigned umin_(unsigned a, unsigned b) { return a < b ? a : b; }
static __device__ __forceinline__ unsigned umax_(unsigned a, unsigned b) { return a > b ? a : b; }

// One block per (slice, batch). Builds the painted-pixel bitmask for its
// 32-row slice in LDS, then streams the 32x512 f32 pred slice with float4
// loads, accumulating sum(sigmoid), sum_painted(sigmoid), painted_count.
__global__ __launch_bounds__(THREADS) void paint_reduce_kernel(
    const float* __restrict__ pred, const int* __restrict__ targets,
    double* __restrict__ partials)
{
    __shared__ int s_x1[NBOXES], s_x2[NBOXES];
    __shared__ unsigned s_y1[NBOXES], s_y2[NBOXES];
    __shared__ int s_nbox;
    __shared__ unsigned s_mask[ROWS_PER_SLICE * 16];  // 32 rows x 512 bits
    __shared__ double s_red[4 * 3];

    const int t = threadIdx.x;
    const int slice = blockIdx.x;
    const int b = blockIdx.y;
    const int r0 = slice * ROWS_PER_SLICE;

    if (t == 0) s_nbox = 0;
    __syncthreads();

    // Load + clip + filter boxes intersecting this slice's row range.
    if (t < NBOXES) {
        const int* g = targets + ((size_t)b * NBOXES + t) * 4;
        int x = g[0], y = g[1], sx = g[2], sy = g[3];
        int x1 = min(x, 512), y1 = min(y, 512);
        int x2 = min(x + sx, 512), y2 = min(y + sy, 512);
        int cx1 = max(x1, r0), cx2 = min(x2, r0 + ROWS_PER_SLICE);
        if (cx2 > cx1 && y2 > y1) {
            int idx = atomicAdd(&s_nbox, 1);
            s_x1[idx] = cx1; s_x2[idx] = cx2;
            s_y1[idx] = (unsigned)y1; s_y2[idx] = (unsigned)y2;
        }
    }
    __syncthreads();

    // Mask build: thread t owns row (t>>3), words (t&7)*2 and +1.
    {
        const int row_l = t >> 3;
        const int w0 = (t & 7) * 2;
        const int r = r0 + row_l;
        unsigned m0 = 0, m1 = 0;
        const unsigned base0 = (unsigned)w0 * 32u;
        const unsigned base1 = base0 + 32u;
        const int nb = s_nbox;
        for (int k = 0; k < nb; ++k) {
            if (r >= s_x1[k] && r < s_x2[k]) {
                unsigned y1 = s_y1[k], y2 = s_y2[k];
                unsigned lo0 = umax_(y1, base0), hi0 = umin_(y2, base0 + 32u);
                if (hi0 > lo0) {
                    unsigned n = hi0 - lo0;
                    unsigned bits = (n == 32u) ? 0xFFFFFFFFu : ((1u << n) - 1u);
                    m0 |= bits << (lo0 - base0);
                }
                unsigned lo1 = umax_(y1, base1), hi1 = umin_(y2, base1 + 32u);
                if (hi1 > lo1) {
                    unsigned n = hi1 - lo1;
                    unsigned bits = (n == 32u) ? 0xFFFFFFFFu : ((1u << n) - 1u);
                    m1 |= bits << (lo1 - base1);
                }
            }
        }
        s_mask[row_l * 16 + w0] = m0;
        s_mask[row_l * 16 + w0 + 1] = m1;
    }
    __syncthreads();

    // Stream the pred slice: 32 rows x 128 float4 per row = 4096 float4.
    const float4* p4 = (const float4*)pred;
    const size_t base4 = (size_t)b * 65536 + (size_t)r0 * 128;
    double psum = 0.0, isum = 0.0;
    int cnt = 0;
    for (int i = t; i < ROWS_PER_SLICE * 128; i += THREADS) {
        const int row_l = i >> 7;
        const int col4 = i & 127;
        float4 v = p4[base4 + (size_t)row_l * 128 + col4];
        const unsigned w = s_mask[row_l * 16 + (col4 >> 3)];
        const unsigned bb = (unsigned)(col4 & 7) * 4u;
        float s0 = 1.0f / (1.0f + __expf(-v.x));
        float s1 = 1.0f / (1.0f + __expf(-v.y));
        float s2 = 1.0f / (1.0f + __expf(-v.z));
        float s3 = 1.0f / (1.0f + __expf(-v.w));
        psum += (double)s0 + (double)s1 + (double)s2 + (double)s3;
        if ((w >> bb) & 1u)        { isum += (double)s0; cnt++; }
        if ((w >> (bb + 1)) & 1u)  { isum += (double)s1; cnt++; }
        if ((w >> (bb + 2)) & 1u)  { isum += (double)s2; cnt++; }
        if ((w >> (bb + 3)) & 1u)  { isum += (double)s3; cnt++; }
    }
    double csum = (double)cnt;

    // Wave (64-lane) reduce, then cross-wave via LDS.
    for (int off = 32; off > 0; off >>= 1) {
        psum += __shfl_down(psum, off);
        isum += __shfl_down(isum, off);
        csum += __shfl_down(csum, off);
    }
    const int wave = t >> 6;
    const int lane = t & 63;
    if (lane == 0) {
        s_red[wave * 3 + 0] = psum;
        s_red[wave * 3 + 1] = isum;
        s_red[wave * 3 + 2] = csum;
    }
    __syncthreads();
    if (t == 0) {
        double P = 0, I = 0, C = 0;
        for (int w = 0; w < 4; ++w) {
            P += s_red[w * 3 + 0];
            I += s_red[w * 3 + 1];
            C += s_red[w * 3 + 2];
        }
        double* o = partials + ((size_t)b * SLICES + slice) * 3;
        o[0] = P; o[1] = I; o[2] = C;
    }
}

// One lane per batch: combine slice partials into the scalar loss.
__global__ __launch_bounds__(64) void final_kernel(
    const double* __restrict__ partials, float* __restrict__ out)
{
    const int b = threadIdx.x;  // 0..63
    double P = 0, I = 0, C = 0;
    for (int s = 0; s < SLICES; ++s) {
        const double* p = partials + ((size_t)b * SLICES + s) * 3;
        P += p[0]; I += p[1]; C += p[2];
    }
    const double inter = 255.0 * I;
    const double tsum  = 255.0 * C;
    double loss = (inter + 1.0) / (P + tsum - inter + 1.0);
    for (int off = 32; off > 0; off >>= 1) loss += __shfl_down(loss, off);
    if (b == 0) out[0] = (float)(1.0 - loss / 64.0);
}

extern "C" void kernel_launch(void* const* d_in, const int* in_sizes, int n_in,
                              void* d_out, int out_size, void* d_ws, size_t ws_size,
                              hipStream_t stream) {
    const float* pred    = (const float*)d_in[0];  // (64,1,512,512) f32
    const int*   targets = (const int*)d_in[1];    // (64,5,32,4) i32
    float* out = (float*)d_out;                    // 1 f32 scalar
    double* partials = (double*)d_ws;              // 64*16*3 doubles = 24 KiB

    dim3 grid(SLICES, 64);
    paint_reduce_kernel<<<grid, THREADS, 0, stream>>>(pred, targets, partials);
    final_kernel<<<1, 64, 0, stream>>>(partials, out);
}

// Round 2
// 108.326 us; speedup vs baseline: 1.0609x; 1.0609x over previous
//
#include <hip/hip_runtime.h>
#include <math.h>

#define SLICES 32
#define ROWS_PER_SLICE 16
#define NBOXES 160
#define THREADS 256
#define F4_PER_BLOCK (ROWS_PER_SLICE * 128)   // 2048
#define F4_PER_THREAD (F4_PER_BLOCK / THREADS) // 8

static __device__ __forceinline__ unsigned umin_(unsigned a, unsigned b) { return a < b ? a : b; }
static __device__ __forceinline__ unsigned umax_(unsigned a, unsigned b) { return a > b ? a : b; }

static __device__ __forceinline__ float fast_sigmoid(float x) {
    // 1 / (1 + e^-x); raw v_rcp_f32 (1 ulp) is plenty for a 1e-4 threshold.
    return __builtin_amdgcn_rcpf(1.0f + __expf(-x));
}

// One block per (slice, batch). Builds the painted-pixel bitmask for its
// 16-row slice in LDS, then streams the 16x512 f32 pred slice with float4
// loads, accumulating sum(sigmoid), sum_painted(sigmoid), painted_count
// in f32/int (error budget: ~1e-8 on the final scalar vs 1e-4 threshold).
__global__ __launch_bounds__(THREADS) void paint_reduce_kernel(
    const float* __restrict__ pred, const int* __restrict__ targets,
    float* __restrict__ partials)
{
    __shared__ int s_x1[NBOXES], s_x2[NBOXES];
    __shared__ unsigned s_y1[NBOXES], s_y2[NBOXES];
    __shared__ int s_nbox;
    __shared__ unsigned s_mask[ROWS_PER_SLICE * 16];  // 16 rows x 512 bits
    __shared__ float s_red[4 * 3];

    const int t = threadIdx.x;
    const int slice = blockIdx.x;
    const int b = blockIdx.y;
    const int r0 = slice * ROWS_PER_SLICE;

    if (t == 0) s_nbox = 0;
    __syncthreads();

    // Load + clip + filter boxes intersecting this slice's row range.
    if (t < NBOXES) {
        const int* g = targets + ((size_t)b * NBOXES + t) * 4;
        int x = g[0], y = g[1], sx = g[2], sy = g[3];
        int x1 = min(x, 512), y1 = min(y, 512);
        int x2 = min(x + sx, 512), y2 = min(y + sy, 512);
        int cx1 = max(x1, r0), cx2 = min(x2, r0 + ROWS_PER_SLICE);
        if (cx2 > cx1 && y2 > y1) {
            int idx = atomicAdd(&s_nbox, 1);
            s_x1[idx] = cx1; s_x2[idx] = cx2;
            s_y1[idx] = (unsigned)y1; s_y2[idx] = (unsigned)y2;
        }
    }
    __syncthreads();

    // Mask build: thread t owns row (t>>4), word (t&15). One word/thread.
    {
        const int row_l = t >> 4;
        const int w = t & 15;
        const int r = r0 + row_l;
        unsigned m = 0;
        const unsigned base = (unsigned)w * 32u;
        const int nb = s_nbox;
        for (int k = 0; k < nb; ++k) {
            if (r >= s_x1[k] && r < s_x2[k]) {
                unsigned lo = umax_(s_y1[k], base), hi = umin_(s_y2[k], base + 32u);
                if (hi > lo) {
                    unsigned n = hi - lo;
                    unsigned bits = (n == 32u) ? 0xFFFFFFFFu : ((1u << n) - 1u);
                    m |= bits << (lo - base);
                }
            }
        }
        s_mask[t] = m;
    }
    __syncthreads();

    // Stream the pred slice. Thread t handles f4 index t + 256k, k=0..7:
    // col4 = t&127 (constant per thread), row = (t>>7) + 2k.
    const float4* p4 = (const float4*)pred;
    const int col4 = t & 127;
    const int row_base = t >> 7;
    const int widx = col4 >> 3;
    const unsigned bb = (unsigned)(col4 & 7) * 4u;
    const size_t base4 = (size_t)b * 65536 + (size_t)r0 * 128 + col4;

    float4 v[F4_PER_THREAD];
    unsigned nib[F4_PER_THREAD];
#pragma unroll
    for (int k = 0; k < F4_PER_THREAD; ++k) {
        const int row = row_base + 2 * k;
        v[k] = p4[base4 + (size_t)row * 128];
        nib[k] = (s_mask[row * 16 + widx] >> bb) & 0xFu;
    }

    float psum = 0.0f, isum = 0.0f;
    int cnt = 0;
#pragma unroll
    for (int k = 0; k < F4_PER_THREAD; ++k) {
        float s0 = fast_sigmoid(v[k].x);
        float s1 = fast_sigmoid(v[k].y);
        float s2 = fast_sigmoid(v[k].z);
        float s3 = fast_sigmoid(v[k].w);
        psum += (s0 + s1) + (s2 + s3);
        const unsigned n = nib[k];
        cnt += __popc(n);
        isum += ((n & 1u) ? s0 : 0.0f) + ((n & 2u) ? s1 : 0.0f)
              + ((n & 4u) ? s2 : 0.0f) + ((n & 8u) ? s3 : 0.0f);
    }
    float csum = (float)cnt;

    // Wave (64-lane) reduce, then cross-wave via LDS.
    for (int off = 32; off > 0; off >>= 1) {
        psum += __shfl_down(psum, off);
        isum += __shfl_down(isum, off);
        csum += __shfl_down(csum, off);
    }
    const int wave = t >> 6;
    const int lane = t & 63;
    if (lane == 0) {
        s_red[wave * 3 + 0] = psum;
        s_red[wave * 3 + 1] = isum;
        s_red[wave * 3 + 2] = csum;
    }
    __syncthreads();
    if (t == 0) {
        float P = 0, I = 0, C = 0;
        for (int w = 0; w < 4; ++w) {
            P += s_red[w * 3 + 0];
            I += s_red[w * 3 + 1];
            C += s_red[w * 3 + 2];
        }
        float* o = partials + ((size_t)b * SLICES + slice) * 3;
        o[0] = P; o[1] = I; o[2] = C;
    }
}

// One lane per batch: combine slice partials into the scalar loss.
__global__ __launch_bounds__(64) void final_kernel(
    const float* __restrict__ partials, float* __restrict__ out)
{
    const int b = threadIdx.x;  // 0..63
    double P = 0, I = 0, C = 0;
    for (int s = 0; s < SLICES; ++s) {
        const float* p = partials + ((size_t)b * SLICES + s) * 3;
        P += (double)p[0]; I += (double)p[1]; C += (double)p[2];
    }
    const double inter = 255.0 * I;
    const double tsum  = 255.0 * C;
    double loss = (inter + 1.0) / (P + tsum - inter + 1.0);
    for (int off = 32; off > 0; off >>= 1) loss += __shfl_down(loss, off);
    if (b == 0) out[0] = (float)(1.0 - loss / 64.0);
}

extern "C" void kernel_launch(void* const* d_in, const int* in_sizes, int n_in,
                              void* d_out, int out_size, void* d_ws, size_t ws_size,
                              hipStream_t stream) {
    const float* pred    = (const float*)d_in[0];  // (64,1,512,512) f32
    const int*   targets = (const int*)d_in[1];    // (64,5,32,4) i32
    float* out = (float*)d_out;                    // 1 f32 scalar
    float* partials = (float*)d_ws;                // 64*32*3 floats = 24 KiB

    dim3 grid(SLICES, 64);
    paint_reduce_kernel<<<grid, THREADS, 0, stream>>>(pred, targets, partials);
    final_kernel<<<1, 64, 0, stream>>>(partials, out);
}

// Round 3
// 107.616 us; speedup vs baseline: 1.0679x; 1.0066x over previous
//
#include <hip/hip_runtime.h>
#include <math.h>

#define SLICES 32
#define ROWS_PER_SLICE 16
#define NBOXES 160
#define THREADS 256

static __device__ __forceinline__ float fast_sigmoid(float x) {
    // 1 / (1 + e^-x); raw v_rcp_f32 (1 ulp) is plenty for a 1e-4 threshold.
    return __builtin_amdgcn_rcpf(1.0f + __expf(-x));
}

// One block per (slice, batch). Builds the painted-pixel bitmask for its
// 16-row slice in LDS (ballot-compacted box list, no atomics), then streams
// the 16x512 f32 pred slice with 8 float4 loads ALL issued before first use
// (sched_barrier pins them) so memory latency is hidden by MLP x TLP.
__global__ __launch_bounds__(THREADS) void paint_reduce_kernel(
    const float* __restrict__ pred, const int* __restrict__ targets,
    float* __restrict__ partials)
{
    __shared__ int s_x1[NBOXES], s_x2[NBOXES];
    __shared__ unsigned s_y1[NBOXES], s_y2[NBOXES];
    __shared__ int s_wcnt[4];
    __shared__ unsigned s_mask[ROWS_PER_SLICE * 16];  // 16 rows x 512 bits
    __shared__ float s_red[4 * 3];

    const int t = threadIdx.x;
    const int slice = blockIdx.x;
    const int b = blockIdx.y;
    const int r0 = slice * ROWS_PER_SLICE;

    // ---- Phase 0: box load + clip + ballot compaction (no LDS atomics) ----
    bool keep = false;
    int cx1 = 0, cx2 = 0;
    unsigned cy1 = 0, cy2 = 0;
    if (t < NBOXES) {
        const int4 g = ((const int4*)targets)[(size_t)b * NBOXES + t];
        int x1 = min(g.x, 512), y1 = min(g.y, 512);
        int x2 = min(g.x + g.z, 512), y2 = min(g.y + g.w, 512);
        cx1 = max(x1, r0); cx2 = min(x2, r0 + ROWS_PER_SLICE);
        cy1 = (unsigned)y1; cy2 = (unsigned)y2;
        keep = (cx2 > cx1) && (y2 > y1);
    }
    const unsigned long long bal = __ballot(keep);
    const int lane = t & 63, wave = t >> 6;
    if (lane == 0) s_wcnt[wave] = (int)__popcll(bal);
    __syncthreads();
    int wbase_cnt = 0;
    for (int w = 0; w < wave; ++w) wbase_cnt += s_wcnt[w];
    const int nb = s_wcnt[0] + s_wcnt[1] + s_wcnt[2] + s_wcnt[3];
    if (keep) {
        const int idx = wbase_cnt + (int)__popcll(bal & ((1ull << lane) - 1ull));
        s_x1[idx] = cx1; s_x2[idx] = cx2; s_y1[idx] = cy1; s_y2[idx] = cy2;
    }
    __syncthreads();

    // ---- Phase 1: mask build. Thread t owns row (t>>4), word (t&15). ----
    {
        const int row_l = t >> 4;
        const int w = t & 15;
        const int r = r0 + row_l;
        const unsigned wb = (unsigned)w * 32u;
        unsigned m = 0;
        for (int k = 0; k < nb; ++k) {
            if (r >= s_x1[k] && r < s_x2[k]) {
                unsigned lo = s_y1[k], hi = s_y2[k];
                lo = lo > wb ? lo : wb;
                hi = hi < wb + 32u ? hi : wb + 32u;
                if (hi > lo) {
                    unsigned n = hi - lo;
                    unsigned bits = (n >= 32u) ? 0xFFFFFFFFu : ((1u << n) - 1u);
                    m |= bits << (lo - wb);
                }
            }
        }
        s_mask[t] = m;
    }
    __syncthreads();

    // ---- Phase 2: stream pred. Thread t: col4 = t&127, rows rb+2k. ----
    const float4* p4 = (const float4*)pred;
    const int col4 = t & 127;
    const int rb = t >> 7;  // 0 or 1
    const int widx = col4 >> 3;
    const unsigned bb = (unsigned)(col4 & 7) * 4u;
    const size_t g0 = (size_t)b * 65536 + (size_t)r0 * 128 + col4;

    float4 v0 = p4[g0 + (size_t)(rb +  0) * 128];
    float4 v1 = p4[g0 + (size_t)(rb +  2) * 128];
    float4 v2 = p4[g0 + (size_t)(rb +  4) * 128];
    float4 v3 = p4[g0 + (size_t)(rb +  6) * 128];
    float4 v4 = p4[g0 + (size_t)(rb +  8) * 128];
    float4 v5 = p4[g0 + (size_t)(rb + 10) * 128];
    float4 v6 = p4[g0 + (size_t)(rb + 12) * 128];
    float4 v7 = p4[g0 + (size_t)(rb + 14) * 128];
    __builtin_amdgcn_sched_barrier(0);
    asm volatile("" ::: "memory");

    unsigned n0 = (s_mask[(rb +  0) * 16 + widx] >> bb) & 0xFu;
    unsigned n1 = (s_mask[(rb +  2) * 16 + widx] >> bb) & 0xFu;
    unsigned n2 = (s_mask[(rb +  4) * 16 + widx] >> bb) & 0xFu;
    unsigned n3 = (s_mask[(rb +  6) * 16 + widx] >> bb) & 0xFu;
    unsigned n4 = (s_mask[(rb +  8) * 16 + widx] >> bb) & 0xFu;
    unsigned n5 = (s_mask[(rb + 10) * 16 + widx] >> bb) & 0xFu;
    unsigned n6 = (s_mask[(rb + 12) * 16 + widx] >> bb) & 0xFu;
    unsigned n7 = (s_mask[(rb + 14) * 16 + widx] >> bb) & 0xFu;

    float psum = 0.0f, isum = 0.0f;
    int cnt = 0;
#define ACC(V, N)                                                       \
    {                                                                   \
        float s0 = fast_sigmoid((V).x);                                 \
        float s1 = fast_sigmoid((V).y);                                 \
        float s2 = fast_sigmoid((V).z);                                 \
        float s3 = fast_sigmoid((V).w);                                 \
        psum += (s0 + s1) + (s2 + s3);                                  \
        cnt += __popc(N);                                               \
        isum += (((N) & 1u) ? s0 : 0.0f) + (((N) & 2u) ? s1 : 0.0f)     \
              + (((N) & 4u) ? s2 : 0.0f) + (((N) & 8u) ? s3 : 0.0f);    \
    }
    ACC(v0, n0) ACC(v1, n1) ACC(v2, n2) ACC(v3, n3)
    ACC(v4, n4) ACC(v5, n5) ACC(v6, n6) ACC(v7, n7)
#undef ACC
    float csum = (float)cnt;

    // ---- Phase 3: wave reduce + cross-wave via LDS. ----
    for (int off = 32; off > 0; off >>= 1) {
        psum += __shfl_down(psum, off);
        isum += __shfl_down(isum, off);
        csum += __shfl_down(csum, off);
    }
    if (lane == 0) {
        s_red[wave * 3 + 0] = psum;
        s_red[wave * 3 + 1] = isum;
        s_red[wave * 3 + 2] = csum;
    }
    __syncthreads();
    if (t == 0) {
        float P = 0, I = 0, C = 0;
        for (int w = 0; w < 4; ++w) {
            P += s_red[w * 3 + 0];
            I += s_red[w * 3 + 1];
            C += s_red[w * 3 + 2];
        }
        float* o = partials + ((size_t)b * SLICES + slice) * 3;
        o[0] = P; o[1] = I; o[2] = C;
    }
}

// One lane per batch: combine slice partials into the scalar loss.
__global__ __launch_bounds__(64) void final_kernel(
    const float* __restrict__ partials, float* __restrict__ out)
{
    const int b = threadIdx.x;  // 0..63
    double P = 0, I = 0, C = 0;
    for (int s = 0; s < SLICES; ++s) {
        const float* p = partials + ((size_t)b * SLICES + s) * 3;
        P += (double)p[0]; I += (double)p[1]; C += (double)p[2];
    }
    const double inter = 255.0 * I;
    const double tsum  = 255.0 * C;
    double loss = (inter + 1.0) / (P + tsum - inter + 1.0);
    for (int off = 32; off > 0; off >>= 1) loss += __shfl_down(loss, off);
    if (b == 0) out[0] = (float)(1.0 - loss / 64.0);
}

extern "C" void kernel_launch(void* const* d_in, const int* in_sizes, int n_in,
                              void* d_out, int out_size, void* d_ws, size_t ws_size,
                              hipStream_t stream) {
    const float* pred    = (const float*)d_in[0];  // (64,1,512,512) f32
    const int*   targets = (const int*)d_in[1];    // (64,5,32,4) i32
    float* out = (float*)d_out;                    // 1 f32 scalar
    float* partials = (float*)d_ws;                // 64*32*3 floats = 24 KiB

    dim3 grid(SLICES, 64);
    paint_reduce_kernel<<<grid, THREADS, 0, stream>>>(pred, targets, partials);
    final_kernel<<<1, 64, 0, stream>>>(partials, out);
}